// Round 3
// baseline (572.369 us; speedup 1.0000x reference)
//
#include <hip/hip_runtime.h>
#include <cstddef>

// ---- problem constants ----
constexpr int kN  = 16;
constexpr int kI  = 128;
constexpr int kHW = 24;
constexpr int kQ  = 576;    // 24*24
constexpr int kD  = 484;    // 22*22
constexpr int kDP = 512;    // padded d
constexpr int kPP = 676;    // 26*26 padded

// GEMM K-tiling
constexpr int kKT1 = 144;   // K1 = 4608 (= 2 src * 9 tap * 256 ic)
constexpr int kKT2 = 8;     // K2 = 256
constexpr int kKT3 = 8;     // K3 = 256

// ---- workspace layout ----
// half region (element offsets into _Float16*)
constexpr size_t H_XPAD   = 0;                          // [16][26][26][256] NHWC
constexpr size_t H_HPAD   = 2768896;                    // [16][26][26][256] NHWC
constexpr size_t H_APACK1 = 5537792;                    // 1792*4608 frag-tiled (256-row tiles)
constexpr size_t H_APACK2 = 13795328;                   // 1024*256 frag-tiled
constexpr size_t H_APACK3 = 14057472;                   // 256*256 frag-tiled
constexpr size_t H_A16    = 14123008;                   // [16][576][256]
constexpr size_t H_H16    = 16482304;                   // [16][576][256]
constexpr size_t H_Q16C   = 18841600;                   // [16][256][576]  (c-major)
constexpr size_t H_KT16   = 21200896;                   // [128 head][512 d][32 c]
constexpr size_t H_VC16   = 23298048;                   // [128 head][32 c][512 d]
constexpr size_t HALF_ELEMS = 25395200;
constexpr size_t HALF_BYTES = HALF_ELEMS * 2;           // 50,790,400
// float region at d_ws + HALF_BYTES
constexpr size_t F_G = 0;                               // [16][1024][576]

using half8    = __attribute__((ext_vector_type(8))) _Float16;
using floatx16 = __attribute__((ext_vector_type(16))) float;

__device__ __forceinline__ float sigm(float x) { return 1.0f / (1.0f + __expf(-x)); }
__device__ __forceinline__ float tanh_f(float x) {
    float e = __expf(2.0f * fabsf(x));
    float r = 1.0f - 2.0f / (e + 1.0f);
    return copysignf(r, x);
}

// 16B-aligned vector load/store (emits b128 ops)
__device__ __forceinline__ half8 LD8(const _Float16* p) { return *(const half8*)p; }

// ---------------- weight packing ----------------
// Apack layout: [mt][kt][kk(2)][hl(2)][row(256)][j(8)] — exact A-fragment order,
// 256-row M-tiles (BM=256).
// K-order for gemm1: k = src*2304 + tap*256 + ic  (maps to source ic*9+tap)
// Gate rows (m>=768) are PERMUTED: dst row m' = 4*r + gate  <-  src row gate*256 + r
// so gemm2's epilogue can compute the LSTM per-lane (gate == reg&3).
__global__ void pack1_kernel(const float* __restrict__ wq_x, const float* __restrict__ wq_h,
                             const float* __restrict__ wk_x, const float* __restrict__ wk_h,
                             const float* __restrict__ wv_x, const float* __restrict__ wv_h,
                             const float* __restrict__ wg_x, const float* __restrict__ wg_h,
                             _Float16* __restrict__ dst) {
    int pidx = blockIdx.x * 256 + threadIdx.x;
    int j = pidx & 7, row = (pidx >> 3) & 255, hl = (pidx >> 11) & 1, kk = (pidx >> 12) & 1;
    int tile = pidx >> 13;
    int mt = tile / kKT1, kt = tile - mt * kKT1;
    int m = mt * 256 + row;
    int k = kt * 32 + kk * 16 + hl * 8 + j;
    int srcs = (k >= 2304) ? 1 : 0;
    int r = k - srcs * 2304;
    int tap = r >> 8, ic = r & 255;
    const float *s1, *s2; int mm;
    if (m < 256)      { s1 = wq_x; s2 = wq_h; mm = m; }
    else if (m < 512) { s1 = wk_x; s2 = wk_h; mm = m - 256; }
    else if (m < 768) { s1 = wv_x; s2 = wv_h; mm = m - 512; }
    else              { s1 = wg_x; s2 = wg_h; int mp = m - 768; mm = (mp & 3) * 256 + (mp >> 2); }
    const float* sp = srcs ? s2 : s1;
    dst[pidx] = (_Float16)sp[(size_t)mm * 2304 + ic * 9 + tap];
}

// PERM=1: dst row m <- src row (m&3)*256 + (m>>2)  (gate interleave for wg_a)
template<int PERM>
__global__ void pack_flat_kernel(const float* __restrict__ src, _Float16* __restrict__ dst,
                                 int Ktot, int Ktiles) {
    int pidx = blockIdx.x * 256 + threadIdx.x;
    int j = pidx & 7, row = (pidx >> 3) & 255, hl = (pidx >> 11) & 1, kk = (pidx >> 12) & 1;
    int tile = pidx >> 13;
    int mt = tile / Ktiles, kt = tile - mt * Ktiles;
    int m = mt * 256 + row;
    int k = kt * 32 + kk * 16 + hl * 8 + j;
    int mm = PERM ? ((m & 3) * 256 + (m >> 2)) : m;
    dst[pidx] = (_Float16)src[(size_t)mm * Ktot + k];
}

// ---------------- input staging ----------------
// h0 [n][256][576] fp32 -> NHWC fp16 padded [n][26][26][256] (borders pre-zeroed)
__global__ void pad_nhwc_kernel(const float* __restrict__ src, _Float16* __restrict__ dst) {
    __shared__ float tile[32][65];
    int pxt = blockIdx.x, ict = blockIdx.y, n = blockIdx.z;
    int tid = threadIdx.x;
    {
        int icl = tid >> 6, pxl = tid & 63;
        #pragma unroll
        for (int rep = 0; rep < 8; ++rep) {
            int ic = ict * 32 + rep * 4 + icl;
            tile[rep * 4 + icl][pxl] = src[((size_t)n * 256 + ic) * kQ + pxt * 64 + pxl];
        }
    }
    __syncthreads();
    {
        int icl = tid & 31, pxl0 = tid >> 5;
        #pragma unroll
        for (int rep = 0; rep < 8; ++rep) {
            int pxl = rep * 8 + pxl0;
            int px = pxt * 64 + pxl;
            int y = px / kHW, x = px - y * kHW;
            dst[((size_t)n * kPP + (size_t)(y + 1) * 26 + (x + 1)) * 256 + ict * 32 + icl] =
                (_Float16)tile[icl][pxl];
        }
    }
}

// xin = 1x1 conv(x, w_in)+b_in -> NHWC fp16 padded
__global__ void conv1x1_pad_kernel(const float* __restrict__ x, const float* __restrict__ w,
                                   const float* __restrict__ b, _Float16* __restrict__ out) {
    int px = blockIdx.x * 64 + threadIdx.x;
    int n = blockIdx.z;
    int oc0 = __builtin_amdgcn_readfirstlane(blockIdx.y * 16 + threadIdx.y * 4);
    const float* ip = x + (size_t)n * kI * kQ + px;
    float acc[4] = {0.f, 0.f, 0.f, 0.f};
    #pragma unroll 4
    for (int ic = 0; ic < kI; ++ic) {
        float xv = ip[(size_t)ic * kQ];
        #pragma unroll
        for (int j = 0; j < 4; ++j) acc[j] = fmaf(xv, w[(size_t)(oc0 + j) * kI + ic], acc[j]);
    }
    int y = px / kHW, xc = px - y * kHW;
    _Float16* op = out + ((size_t)n * kPP + (size_t)(y + 1) * 26 + (xc + 1)) * 256 + oc0;
    #pragma unroll
    for (int j = 0; j < 4; ++j) op[j] = (_Float16)(acc[j] + b[oc0 + j]);
}

// ---------------- fused MFMA GEMM (barrier-free, LDS-free) ----------------
// BM=256, BN=64, BK=32; 256 threads = 4 waves; wave wv owns rows wv*64..+63
// (2 m-frags x 2 n-frags = 4 accs/wave).
// A: direct global fragment loads from packed layout (saddr + const lane offset).
// B: direct global fragment loads (each wave loads its own fragments; the 4x
//    intra-block re-read of the 4 KB/phase B tile hits the per-CU L1).
//    NO LDS, NO __syncthreads in the K-loop: waves are independent streams of
//    {8 global_load_dwordx4 + 8 MFMA} per K-step — latency hidden by TLP.
// Inner 8-ict loop is fully imm-folded (offsets <= 480 B); per-tap address math
// is 2 SALU. Grid: natural order (x=nt fast) keeps blocks kt-synchronized so
// the same A[mt][kt] sub-tile is L1/L2-live chip-wide (R2's chunked swizzle
// regressed FETCH 108->132 MB — reverted).
// BMODE 0: B = on-the-fly im2col from two NHWC fp16 images, K=(src,tap,ic)
// BMODE 1: B = direct [n][576][Ktot] fp16 (channel-last)
// EMODE 0: m<256 -> q16c; 256..511 -> kT16; 512..767 -> vC16(+bias); 768.. -> gbuf
// EMODE 2: out = acc + bias[m] -> pf
// EMODE 3: fused gate+LSTM epilogue (gate rows interleaved m'=4r+g)
template<int BMODE, int EMODE>
__global__ __launch_bounds__(256, 4)
void gemm_kernel(const _Float16* __restrict__ Apack,
                 const _Float16* __restrict__ B1, const _Float16* __restrict__ B2,
                 _Float16* __restrict__ q16, _Float16* __restrict__ k16,
                 _Float16* __restrict__ v16, float* __restrict__ pf,
                 const float* __restrict__ bias, const float* __restrict__ c0p,
                 _Float16* __restrict__ h16o, int Ktiles, int Ktot) {
    const int tid = threadIdx.x;
    const int wv = tid >> 6, lane = tid & 63, l31 = lane & 31, hl = lane >> 5;
    const int nt = blockIdx.x, n = blockIdx.y, mt = blockIdx.z;

    floatx16 acc00 = {}, acc01 = {}, acc10 = {}, acc11 = {};

    // A: uniform base walked 8192 elems/K-step + constant per-lane offset
    const _Float16* abase = Apack + (size_t)mt * Ktiles * 8192;
    const int aoff = hl * 2048 + (wv * 64 + l31) * 8;

    // B: constant per-lane pixel offsets (ci=0/1) + uniform per-k-chunk base
    const int px0 = nt * 64 + l31;
    const int px1 = px0 + 32;
    int bpx0, bpx1;
    if (BMODE == 0) {
        int by0 = px0 / kHW, bx0 = px0 - by0 * kHW;
        int by1 = px1 / kHW, bx1 = px1 - by1 * kHW;
        bpx0 = (by0 * 26 + bx0) * 256 + hl * 8;
        bpx1 = (by1 * 26 + bx1) * 256 + hl * 8;
    } else {
        bpx0 = px0 * Ktot + hl * 8;
        bpx1 = px1 * Ktot + hl * 8;
    }

    // one BK=32 step: 8 fragment loads + 8 MFMAs
    auto step = [&](const _Float16* bb) {
        half8 b00 = LD8(bb + bpx0);
        half8 b01 = LD8(bb + bpx1);
        half8 b10 = LD8(bb + bpx0 + 16);
        half8 b11 = LD8(bb + bpx1 + 16);
        half8 a0 = LD8(abase + aoff);
        half8 a2 = LD8(abase + aoff + 256);
        half8 a1 = LD8(abase + aoff + 4096);
        half8 a3 = LD8(abase + aoff + 4096 + 256);
        abase += 8192;
        acc00 = __builtin_amdgcn_mfma_f32_32x32x16_f16(a0, b00, acc00, 0, 0, 0);
        acc01 = __builtin_amdgcn_mfma_f32_32x32x16_f16(a0, b01, acc01, 0, 0, 0);
        acc10 = __builtin_amdgcn_mfma_f32_32x32x16_f16(a2, b00, acc10, 0, 0, 0);
        acc11 = __builtin_amdgcn_mfma_f32_32x32x16_f16(a2, b01, acc11, 0, 0, 0);
        acc00 = __builtin_amdgcn_mfma_f32_32x32x16_f16(a1, b10, acc00, 0, 0, 0);
        acc01 = __builtin_amdgcn_mfma_f32_32x32x16_f16(a1, b11, acc01, 0, 0, 0);
        acc10 = __builtin_amdgcn_mfma_f32_32x32x16_f16(a3, b10, acc10, 0, 0, 0);
        acc11 = __builtin_amdgcn_mfma_f32_32x32x16_f16(a3, b11, acc11, 0, 0, 0);
    };

    if (BMODE == 0) {
        #pragma unroll 1
        for (int src = 0; src < 2; ++src) {
            const _Float16* img = (src ? B2 : B1) + (size_t)n * kPP * 256;
            #pragma unroll 1
            for (int tap = 0; tap < 9; ++tap) {
                int ty = (tap * 11) >> 5, tx = tap - ty * 3;   // tap/3, tap%3
                const _Float16* tb = img + (ty * 26 + tx) * 256;
                #pragma unroll
                for (int ict = 0; ict < 8; ++ict)
                    step(tb + ict * 32);
            }
        }
    } else {
        const _Float16* bb = B1 + (size_t)n * kQ * Ktot;
        #pragma unroll 4
        for (int kt = 0; kt < Ktiles; ++kt)
            step(bb + kt * 32);
    }

    // epilogue: C/D layout col=lane&31, row=(reg&3)+8*(reg>>2)+4*(lane>>5)
    if (EMODE == 3) {
        // fused gates+LSTM: reg q holds gate g=q&3 of channel rr (4 gates per reg-quad)
        const int rrb = mt * 64 + wv * 16;
        #pragma unroll
        for (int mi = 0; mi < 2; ++mi) {
            #pragma unroll
            for (int ci = 0; ci < 2; ++ci) {
                const floatx16& av = mi ? (ci ? acc11 : acc10) : (ci ? acc01 : acc00);
                const int pxe = nt * 64 + ci * 32 + l31;
                #pragma unroll
                for (int tq = 0; tq < 4; ++tq) {
                    int rr = rrb + mi * 8 + 2 * tq + hl;
                    size_t gb = ((size_t)n * 1024 + 4 * rr) * kQ + pxe;
                    float iv = av[4 * tq + 0] + pf[gb]          + bias[rr];
                    float fv = av[4 * tq + 1] + pf[gb + kQ]     + bias[256 + rr];
                    float gv = av[4 * tq + 2] + pf[gb + 2 * kQ] + bias[512 + rr];
                    float ov = av[4 * tq + 3] + pf[gb + 3 * kQ] + bias[768 + rr];
                    float cc = sigm(fv) * c0p[((size_t)n * 256 + rr) * kQ + pxe]
                             + sigm(iv) * tanh_f(gv);
                    float hh = sigm(ov) * tanh_f(cc);
                    h16o[((size_t)n * kQ + pxe) * 256 + rr] = (_Float16)hh;
                }
            }
        }
        return;
    }
    const int mb0 = mt * 256 + wv * 64;
    #pragma unroll
    for (int mi = 0; mi < 2; ++mi) {
        #pragma unroll
        for (int ci = 0; ci < 2; ++ci) {
            const floatx16& av = mi ? (ci ? acc11 : acc10) : (ci ? acc01 : acc00);
            const int pxe = nt * 64 + ci * 32 + l31;
            #pragma unroll
            for (int r = 0; r < 16; ++r) {
                int rowi = (r & 3) + 8 * (r >> 2) + 4 * hl;
                int m = mb0 + mi * 32 + rowi;
                float val = av[r];
                if (EMODE == 0) {
                    if (m < 256) {
                        q16[((size_t)n * 256 + m) * kQ + pxe] = (_Float16)val;
                    } else if (m < 768) {
                        int ch = m & 255;
                        int yy = pxe / kHW, xx = pxe - yy * kHW;
                        if (yy >= 1 && yy <= 22 && xx >= 1 && xx <= 22) {
                            int d = (yy - 1) * 22 + (xx - 1);
                            int head = n * 8 + (ch >> 5);
                            if (m < 512)
                                k16[((size_t)head * kDP + d) * 32 + (ch & 31)] = (_Float16)val;
                            else
                                v16[((size_t)head * 32 + (ch & 31)) * kDP + d] = (_Float16)(val + bias[ch]);
                        }
                    } else {
                        pf[((size_t)n * 1024 + (m - 768)) * kQ + pxe] = val;
                    }
                } else {
                    pf[((size_t)n * 256 + m) * kQ + pxe] = val + bias[m];
                }
            }
        }
    }
}

// ---------------- MFMA flash attention ----------------
__global__ __launch_bounds__(128)
void attn_kernel(const _Float16* __restrict__ q16c, const _Float16* __restrict__ kT16,
                 const _Float16* __restrict__ vC16, _Float16* __restrict__ a16) {
    const int lane = threadIdx.x & 63;
    const int wv   = threadIdx.x >> 6;
    const int l31 = lane & 31, hl = lane >> 5;
    // XCD-chunked swizzle (1152 blocks, 144/XCD): same-head blocks stay on one XCD
    const int lid = blockIdx.x + 9 * blockIdx.y;
    const int swz = (lid & 7) * 144 + (lid >> 3);
    const int bx = swz % 9, head = swz / 9;     // head = n*8 + hd
    const int n = head >> 3, hd = head & 7;
    const int qt = bx * 2 + wv;                 // 0..17
    const int q0 = qt * 32;

    half8 qf0, qf1;
    {
        const _Float16* qb = q16c + ((size_t)n * 256 + hd * 32 + hl * 8) * kQ + q0 + l31;
        #pragma unroll
        for (int j = 0; j < 8; ++j) {
            qf0[j] = qb[(size_t)j * kQ];
            qf1[j] = qb[(size_t)(16 + j) * kQ];
        }
    }

    const _Float16* kbase0 = kT16 + ((size_t)head * kDP + l31) * 32 + hl * 8;
    const _Float16* vbase0 = vC16 + ((size_t)head * 32 + l31) * kDP + hl * 8;

    floatx16 acc = {};
    float m_run = -1e30f, l_run = 0.f;

    half8 kf0 = LD8(kbase0);
    half8 kf1 = LD8(kbase0 + 16);

    for (int dt = 0; dt < 16; ++dt) {
        const int d0 = dt * 32;
        floatx16 S = {};
        S = __builtin_amdgcn_mfma_f32_32x32x16_f16(kf0, qf0, S, 0, 0, 0);
        S = __builtin_amdgcn_mfma_f32_32x32x16_f16(kf1, qf1, S, 0, 0, 0);

        half8 vf0 = LD8(vbase0 + d0);
        half8 vf1 = LD8(vbase0 + d0 + 16);
        if (dt < 15) {
            kf0 = LD8(kbase0 + (size_t)(d0 + 32) * 32);
            kf1 = LD8(kbase0 + (size_t)(d0 + 32) * 32 + 16);
        }

        if (dt == 15) {
            #pragma unroll
            for (int r = 0; r < 16; ++r)
                if (!(hl == 0 && r < 4)) S[r] = -1e30f;
        }

        float tmax = S[0];
        #pragma unroll
        for (int r = 1; r < 16; ++r) tmax = fmaxf(tmax, S[r]);
        tmax = fmaxf(tmax, __shfl_xor(tmax, 32));
        float mnew = fmaxf(m_run, tmax);
        float f = __expf(m_run - mnew);
        float p[16], psum = 0.f;
        #pragma unroll
        for (int r = 0; r < 16; ++r) { p[r] = __expf(S[r] - mnew); psum += p[r]; }
        psum += __shfl_xor(psum, 32);
        l_run = f * l_run + psum;
        #pragma unroll
        for (int r = 0; r < 16; ++r) acc[r] *= f;
        m_run = mnew;

        float other[16];
        #pragma unroll
        for (int r = 0; r < 16; ++r) other[r] = __shfl_xor(p[r], 32);
        half8 pf0, pf1;
        #pragma unroll
        for (int t = 0; t < 4; ++t) {
            pf0[t]     = (_Float16)(hl ? other[4 + t]  : p[t]);
            pf0[4 + t] = (_Float16)(hl ? p[4 + t]      : other[t]);
            pf1[t]     = (_Float16)(hl ? other[12 + t] : p[8 + t]);
            pf1[4 + t] = (_Float16)(hl ? p[12 + t]     : other[8 + t]);
        }

        acc = __builtin_amdgcn_mfma_f32_32x32x16_f16(vf0, pf0, acc, 0, 0, 0);
        acc = __builtin_amdgcn_mfma_f32_32x32x16_f16(vf1, pf1, acc, 0, 0, 0);
    }

    float inv = 1.f / l_run;
    _Float16* ap = a16 + ((size_t)n * kQ + q0 + l31) * 256 + hd * 32;
    #pragma unroll
    for (int r = 0; r < 16; ++r) {
        int c = (r & 3) + 8 * (r >> 2) + 4 * hl;
        ap[c] = (_Float16)(acc[r] * inv);
    }
}

extern "C" void kernel_launch(void* const* d_in, const int* in_sizes, int n_in,
                              void* d_out, int out_size, void* d_ws, size_t ws_size,
                              hipStream_t stream) {
    (void)in_sizes; (void)n_in; (void)out_size; (void)ws_size;
    const float* x     = (const float*)d_in[0];
    const float* h0    = (const float*)d_in[1];
    const float* c0    = (const float*)d_in[2];
    const float* w_in  = (const float*)d_in[3];
    const float* b_in  = (const float*)d_in[4];
    const float* wq_x  = (const float*)d_in[5];
    const float* wq_h  = (const float*)d_in[6];
    const float* wk_x  = (const float*)d_in[7];
    const float* wk_h  = (const float*)d_in[8];
    const float* wv_x  = (const float*)d_in[9];
    const float* wv_h  = (const float*)d_in[10];
    const float* bv    = (const float*)d_in[11];
    const float* wg_a  = (const float*)d_in[12];
    const float* bg    = (const float*)d_in[13];
    const float* wg_x  = (const float*)d_in[14];
    const float* wg_h  = (const float*)d_in[15];
    const float* w_out = (const float*)d_in[16];
    const float* b_out = (const float*)d_in[17];

    _Float16* wh = (_Float16*)d_ws;
    _Float16* xpad16  = wh + H_XPAD;
    _Float16* hpad16  = wh + H_HPAD;
    _Float16* apack1  = wh + H_APACK1;
    _Float16* apack2  = wh + H_APACK2;
    _Float16* apack3  = wh + H_APACK3;
    _Float16* a16     = wh + H_A16;
    _Float16* h16     = wh + H_H16;
    _Float16* q16c    = wh + H_Q16C;
    _Float16* kT16    = wh + H_KT16;
    _Float16* vC16    = wh + H_VC16;
    float* gbuf = (float*)((char*)d_ws + HALF_BYTES) + F_G;

    // zero NHWC image borders (ws re-poisoned each launch)
    hipMemsetAsync(wh, 0, 11075584, stream);

    // weight packing (fragment-order, 256-row tiles; gate rows interleaved)
    pack1_kernel<<<32256, 256, 0, stream>>>(wq_x, wq_h, wk_x, wk_h, wv_x, wv_h, wg_x, wg_h, apack1);
    pack_flat_kernel<1><<<1024, 256, 0, stream>>>(wg_a, apack2, 256, kKT2);
    pack_flat_kernel<0><<<256, 256, 0, stream>>>(w_out, apack3, 256, kKT3);

    // input staging (NHWC fp16)
    pad_nhwc_kernel<<<dim3(9, 8, kN), 256, 0, stream>>>(h0, hpad16);
    conv1x1_pad_kernel<<<dim3(9, 16, kN), dim3(64, 4), 0, stream>>>(x, w_in, b_in, xpad16);

    // fused q/k/v/gates3x3 GEMM: M=1792, K=4608, N=576 x 16 batches
    // natural grid order (x=nt fast) — blocks stay kt-synchronized for L1/L2 A-sharing
    gemm_kernel<0, 0><<<dim3(9, kN, 7), 256, 0, stream>>>(
        apack1, xpad16, hpad16, q16c, kT16, vC16, gbuf, bv, nullptr, nullptr, kKT1, 0);

    // MFMA flash attention -> a16 [n][px][256]
    attn_kernel<<<dim3(9, 128), 128, 0, stream>>>(q16c, kT16, vC16, a16);

    // gates = wg_a . a + bg + gbuf, fused LSTM -> h16 [n][px][256]
    gemm_kernel<1, 3><<<dim3(9, kN, 4), 256, 0, stream>>>(
        apack2, a16, nullptr, nullptr, nullptr, nullptr, gbuf, bg, c0, h16, kKT2, 256);

    // out = w_out . h + b_out : M=256 -> 1 m-tile
    gemm_kernel<1, 2><<<dim3(9, kN, 1), 256, 0, stream>>>(
        apack3, h16, nullptr, nullptr, nullptr, nullptr, (float*)d_out, b_out, nullptr, nullptr, kKT3, 256);
}

// Round 4
// 419.706 us; speedup vs baseline: 1.3637x; 1.3637x over previous
//
#include <hip/hip_runtime.h>
#include <cstddef>

// ---- problem constants ----
constexpr int kN  = 16;
constexpr int kI  = 128;
constexpr int kHW = 24;
constexpr int kQ  = 576;    // 24*24
constexpr int kD  = 484;    // 22*22
constexpr int kDP = 512;    // padded d
constexpr int kPP = 676;    // 26*26 padded

// GEMM K-tiling
constexpr int kKT1 = 144;   // K1 = 4608 (= 2 src * 9 tap * 256 ic)
constexpr int kKT2 = 8;     // K2 = 256
constexpr int kKT3 = 8;     // K3 = 256

// ---- workspace layout ----
// half region (element offsets into _Float16*)
constexpr size_t H_XPAD   = 0;                          // [16][26][26][256] NHWC
constexpr size_t H_HPAD   = 2768896;                    // [16][26][26][256] NHWC
constexpr size_t H_APACK1 = 5537792;                    // 1792*4608 frag-tiled (256-row tiles)
constexpr size_t H_APACK2 = 13795328;                   // 1024*256 frag-tiled
constexpr size_t H_APACK3 = 14057472;                   // 256*256 frag-tiled
constexpr size_t H_A16    = 14123008;                   // [16][576][256]
constexpr size_t H_H16    = 16482304;                   // [16][576][256]
constexpr size_t H_Q16C   = 18841600;                   // [16][256][576]  (c-major)
constexpr size_t H_KT16   = 21200896;                   // [128 head][512 d][32 c]
constexpr size_t H_VC16   = 23298048;                   // [128 head][32 c][512 d]
constexpr size_t HALF_ELEMS = 25395200;
constexpr size_t HALF_BYTES = HALF_ELEMS * 2;           // 50,790,400
// float region at d_ws + HALF_BYTES
constexpr size_t F_G = 0;                               // [16][1024][576]

constexpr size_t kXHGap = H_HPAD - H_XPAD;              // hpad - xpad element gap

using half8    = __attribute__((ext_vector_type(8))) _Float16;
using floatx16 = __attribute__((ext_vector_type(16))) float;

__device__ __forceinline__ float sigm(float x) { return 1.0f / (1.0f + __expf(-x)); }
__device__ __forceinline__ float tanh_f(float x) {
    float e = __expf(2.0f * fabsf(x));
    float r = 1.0f - 2.0f / (e + 1.0f);
    return copysignf(r, x);
}

// 16B-aligned vector load/store (emits b128 ops)
__device__ __forceinline__ half8 LD8(const _Float16* p) { return *(const half8*)p; }
__device__ __forceinline__ void ST8(_Float16* p, half8 v) { *(half8*)p = v; }

// ---------------- weight packing ----------------
// Apack layout: [mt][kt][kk(2)][hl(2)][row(256)][j(8)] — exact A-fragment order,
// 256-row M-tiles (BM=256). One half8 (j=0..7) per thread.
// K-order for gemm1: k = src*2304 + tap*256 + ic  (maps to source ic*9+tap)
// Gate rows (m>=768) are PERMUTED: dst row m' = 4*r + gate  <-  src row gate*256 + r
// so gemm2's epilogue can compute the LSTM per-lane (gate == reg&3).
__global__ void pack1_kernel(const float* __restrict__ wq_x, const float* __restrict__ wq_h,
                             const float* __restrict__ wk_x, const float* __restrict__ wk_h,
                             const float* __restrict__ wv_x, const float* __restrict__ wv_h,
                             const float* __restrict__ wg_x, const float* __restrict__ wg_h,
                             _Float16* __restrict__ dst) {
    int p8 = blockIdx.x * 256 + threadIdx.x;           // one half8 per thread
    int row = p8 & 255, hl = (p8 >> 8) & 1, kk = (p8 >> 9) & 1;
    int tile = p8 >> 10;
    int mt = tile / kKT1, kt = tile - mt * kKT1;
    int m = mt * 256 + row;
    int k0 = kt * 32 + kk * 16 + hl * 8;               // j=0..7 contiguous in k
    int srcs = (k0 >= 2304) ? 1 : 0;
    int r = k0 - srcs * 2304;
    int tap = r >> 8, ic0 = r & 255;                   // 8-aligned: tap/srcs j-invariant
    const float *s1, *s2; int mm;
    if (m < 256)      { s1 = wq_x; s2 = wq_h; mm = m; }
    else if (m < 512) { s1 = wk_x; s2 = wk_h; mm = m - 256; }
    else if (m < 768) { s1 = wv_x; s2 = wv_h; mm = m - 512; }
    else              { s1 = wg_x; s2 = wg_h; int mp = m - 768; mm = (mp & 3) * 256 + (mp >> 2); }
    const float* sp = (srcs ? s2 : s1) + (size_t)mm * 2304 + ic0 * 9 + tap;
    half8 v;
    #pragma unroll
    for (int j = 0; j < 8; ++j) v[j] = (_Float16)sp[j * 9];
    ST8(dst + (size_t)p8 * 8, v);
}

// PERM=1: dst row m <- src row (m&3)*256 + (m>>2)  (gate interleave for wg_a)
template<int PERM>
__global__ void pack_flat_kernel(const float* __restrict__ src, _Float16* __restrict__ dst,
                                 int Ktot, int Ktiles) {
    int p8 = blockIdx.x * 256 + threadIdx.x;           // one half8 per thread
    int row = p8 & 255, hl = (p8 >> 8) & 1, kk = (p8 >> 9) & 1;
    int tile = p8 >> 10;
    int mt = tile / Ktiles, kt = tile - mt * Ktiles;
    int m = mt * 256 + row;
    int k0 = kt * 32 + kk * 16 + hl * 8;
    int mm = PERM ? ((m & 3) * 256 + (m >> 2)) : m;
    const float* sp = src + (size_t)mm * Ktot + k0;
    half8 v;
    #pragma unroll
    for (int j = 0; j < 8; ++j) v[j] = (_Float16)sp[j];
    ST8(dst + (size_t)p8 * 8, v);
}

// ---------------- input staging ----------------
// h0 [n][256][576] fp32 -> NHWC fp16 padded [n][26][26][256] (borders pre-zeroed)
__global__ void pad_nhwc_kernel(const float* __restrict__ src, _Float16* __restrict__ dst) {
    __shared__ float tile[32][65];
    int pxt = blockIdx.x, ict = blockIdx.y, n = blockIdx.z;
    int tid = threadIdx.x;
    {
        int icl = tid >> 6, pxl = tid & 63;
        #pragma unroll
        for (int rep = 0; rep < 8; ++rep) {
            int ic = ict * 32 + rep * 4 + icl;
            tile[rep * 4 + icl][pxl] = src[((size_t)n * 256 + ic) * kQ + pxt * 64 + pxl];
        }
    }
    __syncthreads();
    {
        int icl = tid & 31, pxl0 = tid >> 5;
        #pragma unroll
        for (int rep = 0; rep < 8; ++rep) {
            int pxl = rep * 8 + pxl0;
            int px = pxt * 64 + pxl;
            int y = px / kHW, x = px - y * kHW;
            dst[((size_t)n * kPP + (size_t)(y + 1) * 26 + (x + 1)) * 256 + ict * 32 + icl] =
                (_Float16)tile[icl][pxl];
        }
    }
}

// xin = 1x1 conv(x, w_in)+b_in -> NHWC fp16 padded
__global__ void conv1x1_pad_kernel(const float* __restrict__ x, const float* __restrict__ w,
                                   const float* __restrict__ b, _Float16* __restrict__ out) {
    int px = blockIdx.x * 64 + threadIdx.x;
    int n = blockIdx.z;
    int oc0 = __builtin_amdgcn_readfirstlane(blockIdx.y * 16 + threadIdx.y * 4);
    const float* ip = x + (size_t)n * kI * kQ + px;
    float acc[4] = {0.f, 0.f, 0.f, 0.f};
    #pragma unroll 4
    for (int ic = 0; ic < kI; ++ic) {
        float xv = ip[(size_t)ic * kQ];
        #pragma unroll
        for (int j = 0; j < 4; ++j) acc[j] = fmaf(xv, w[(size_t)(oc0 + j) * kI + ic], acc[j]);
    }
    int y = px / kHW, xc = px - y * kHW;
    _Float16* op = out + ((size_t)n * kPP + (size_t)(y + 1) * 26 + (xc + 1)) * 256 + oc0;
    #pragma unroll
    for (int j = 0; j < 4; ++j) op[j] = (_Float16)(acc[j] + b[oc0 + j]);
}

// ---------------- fused MFMA GEMM ----------------
// BM=256, BN=64, BK=32; 256 threads = 4 waves; wave wv owns rows wv*64..+63
// (2 m-frags x 2 n-frags = 4 accs/wave; LDS B reads amortized over 2 m-frags).
// A: direct global fragment loads from packed layout, 1-step register prefetch.
// B: one half8/thread -> swizzled LDS, double-buffered, 2-step register prefetch.
// KEY (R4): raw s_barrier + manual lgkmcnt(0) instead of __syncthreads(), so the
// compiler keeps COUNTED vmcnt for the A/B register prefetches (the __syncthreads
// vmcnt(0)-drain was the 2-phase ceiling: every K-step paid a full load latency).
// ONE barrier per K-step: the lgkmcnt(0) before each barrier retires this wave's
// ds_reads AND its ds_write, so buffer b's readers are provably done one barrier
// before its next writer (writes to b happen 2 barriers after its reads issue).
// setprio(1) around the MFMA cluster (T5: 4 independent blocks/CU arbitrate).
// BMODE 0: B = on-the-fly im2col from two NHWC fp16 images, K=(src,tap,ic)
// BMODE 1: B = direct [n][576][Ktot] fp16 (channel-last)
// EMODE 0: m<256 -> q16c; 256..511 -> kT16; 512..767 -> vC16(+bias); 768.. -> gbuf
// EMODE 2: out = acc + bias[m] -> pf
// EMODE 3: fused gate+LSTM epilogue (gate rows interleaved m'=4r+g)
template<int BMODE, int EMODE>
__global__ __launch_bounds__(256, 4)
void gemm_kernel(const _Float16* __restrict__ Apack,
                 const _Float16* __restrict__ B1, const _Float16* __restrict__ B2,
                 _Float16* __restrict__ q16, _Float16* __restrict__ k16,
                 _Float16* __restrict__ v16, float* __restrict__ pf,
                 const float* __restrict__ bias, const float* __restrict__ c0p,
                 _Float16* __restrict__ h16o, int Ktiles, int Ktot) {
    __shared__ _Float16 Bs[2][2048];
    const int tid = threadIdx.x;
    const int wv = tid >> 6, lane = tid & 63, l31 = lane & 31, hl = lane >> 5;
    const int nt = blockIdx.x, n = blockIdx.y, mt = blockIdx.z;

    floatx16 acc00 = {}, acc01 = {}, acc10 = {}, acc11 = {};

    // A packed [mt][kt][kk][hl][row256][j8]; per-kt tile = 8192 elems
    const _Float16* ap0 = Apack + (size_t)mt * Ktiles * 8192
                        + (size_t)hl * 2048 + (size_t)(wv * 64 + l31) * 8;   // kk=0
    const _Float16* ap1 = ap0 + 4096;                                        // kk=1

    const int px_l = tid >> 2, bc = tid & 3;
    const int px = nt * 64 + px_l;
    const int by = px / kHW, bx = px - by * kHW;

    // swizzled LDS offsets
    const int wofs = px_l * 32 + ((bc ^ ((px_l >> 1) & 3)) << 3);
    const int sw = (l31 >> 1) & 3;
    const int r00 = l31 * 32        + ((hl ^ sw) << 3);        // kk=0, cols 0..31
    const int r01 = (32 + l31) * 32 + ((hl ^ sw) << 3);        // kk=0, cols 32..63
    const int r10 = l31 * 32        + (((2 + hl) ^ sw) << 3);  // kk=1
    const int r11 = (32 + l31) * 32 + (((2 + hl) ^ sw) << 3);

    const _Float16* bsx;
    if (BMODE == 0) {
        bsx = B1 + ((size_t)n * kPP + (size_t)by * 26 + bx) * 256 + (size_t)bc * 8;
    } else {
        bsx = B1 + ((size_t)n * kQ + px) * Ktot + bc * 8;
    }

    auto loadB = [&](int kt) -> half8 {
        if (BMODE == 0) {
            int srcs = (kt >= 72) ? 1 : 0;
            int t2 = kt - srcs * 72;
            int tap = t2 >> 3, ict = t2 & 7;
            int ty = (tap * 11) >> 5;          // tap/3 for 0..8
            int tx = tap - ty * 3;
            const _Float16* p = bsx + (size_t)srcs * kXHGap
                              + ((size_t)(ty * 26 + tx)) * 256 + ict * 32;
            return LD8(p);
        } else {
            return LD8(bsx + kt * 32);
        }
    };

    // prologue: B two tiles deep, A one tile
    half8 bv0 = loadB(0);
    half8 bv1 = loadB(1);
    half8 a0 = LD8(ap0), a2 = LD8(ap0 + 256);   // mi=0/1, kk=0
    half8 a1 = LD8(ap1), a3 = LD8(ap1 + 256);   // mi=0/1, kk=1
    half8 c0, c1, c2, c3;

    for (int kt = 0; kt < Ktiles; kt += 2) {
        // ---- even step: buffer 0 holds tile kt ----
        ST8(&Bs[0][wofs], bv0);                             // counted vmcnt for bv0 only
        bv0 = loadB(kt + 2);                                // 2-deep B prefetch (stays in flight)
        asm volatile("s_waitcnt lgkmcnt(0)" ::: "memory");  // ds_write visible; my ds_reads retired
        __builtin_amdgcn_s_barrier();                       // raw: no vmcnt drain
        {
            const _Float16* bb = Bs[0];
            half8 b00 = LD8(bb + r00);
            half8 b01 = LD8(bb + r01);
            half8 b10 = LD8(bb + r10);
            half8 b11 = LD8(bb + r11);
            c0 = LD8(ap0 + 8192); c2 = LD8(ap0 + 8448);     // A(kt+1) prefetch
            c1 = LD8(ap1 + 8192); c3 = LD8(ap1 + 8448);
            __builtin_amdgcn_s_setprio(1);
            acc00 = __builtin_amdgcn_mfma_f32_32x32x16_f16(a0, b00, acc00, 0, 0, 0);
            acc01 = __builtin_amdgcn_mfma_f32_32x32x16_f16(a0, b01, acc01, 0, 0, 0);
            acc10 = __builtin_amdgcn_mfma_f32_32x32x16_f16(a2, b00, acc10, 0, 0, 0);
            acc11 = __builtin_amdgcn_mfma_f32_32x32x16_f16(a2, b01, acc11, 0, 0, 0);
            acc00 = __builtin_amdgcn_mfma_f32_32x32x16_f16(a1, b10, acc00, 0, 0, 0);
            acc01 = __builtin_amdgcn_mfma_f32_32x32x16_f16(a1, b11, acc01, 0, 0, 0);
            acc10 = __builtin_amdgcn_mfma_f32_32x32x16_f16(a3, b10, acc10, 0, 0, 0);
            acc11 = __builtin_amdgcn_mfma_f32_32x32x16_f16(a3, b11, acc11, 0, 0, 0);
            __builtin_amdgcn_s_setprio(0);
        }
        // ---- odd step: buffer 1 holds tile kt+1 ----
        ST8(&Bs[1][wofs], bv1);
        bv1 = loadB(kt + 3);
        asm volatile("s_waitcnt lgkmcnt(0)" ::: "memory");
        __builtin_amdgcn_s_barrier();
        {
            const _Float16* bb = Bs[1];
            half8 b00 = LD8(bb + r00);
            half8 b01 = LD8(bb + r01);
            half8 b10 = LD8(bb + r10);
            half8 b11 = LD8(bb + r11);
            a0 = LD8(ap0 + 16384); a2 = LD8(ap0 + 16640);   // A(kt+2) prefetch (OOB-safe: ws)
            a1 = LD8(ap1 + 16384); a3 = LD8(ap1 + 16640);
            __builtin_amdgcn_s_setprio(1);
            acc00 = __builtin_amdgcn_mfma_f32_32x32x16_f16(c0, b00, acc00, 0, 0, 0);
            acc01 = __builtin_amdgcn_mfma_f32_32x32x16_f16(c0, b01, acc01, 0, 0, 0);
            acc10 = __builtin_amdgcn_mfma_f32_32x32x16_f16(c2, b00, acc10, 0, 0, 0);
            acc11 = __builtin_amdgcn_mfma_f32_32x32x16_f16(c2, b01, acc11, 0, 0, 0);
            acc00 = __builtin_amdgcn_mfma_f32_32x32x16_f16(c1, b10, acc00, 0, 0, 0);
            acc01 = __builtin_amdgcn_mfma_f32_32x32x16_f16(c1, b11, acc01, 0, 0, 0);
            acc10 = __builtin_amdgcn_mfma_f32_32x32x16_f16(c3, b10, acc10, 0, 0, 0);
            acc11 = __builtin_amdgcn_mfma_f32_32x32x16_f16(c3, b11, acc11, 0, 0, 0);
            __builtin_amdgcn_s_setprio(0);
        }
        ap0 += 16384; ap1 += 16384;
    }

    // epilogue: C/D layout col=lane&31, row=(reg&3)+8*(reg>>2)+4*(lane>>5)
    if (EMODE == 3) {
        // fused gates+LSTM: reg q holds gate g=q&3 of channel rr (4 gates per reg-quad)
        const int rrb = mt * 64 + wv * 16;
        #pragma unroll
        for (int mi = 0; mi < 2; ++mi) {
            #pragma unroll
            for (int ci = 0; ci < 2; ++ci) {
                const floatx16& av = mi ? (ci ? acc11 : acc10) : (ci ? acc01 : acc00);
                const int pxe = nt * 64 + ci * 32 + l31;
                #pragma unroll
                for (int tq = 0; tq < 4; ++tq) {
                    int rr = rrb + mi * 8 + 2 * tq + hl;
                    size_t gb = ((size_t)n * 1024 + 4 * rr) * kQ + pxe;
                    float iv = av[4 * tq + 0] + pf[gb]          + bias[rr];
                    float fv = av[4 * tq + 1] + pf[gb + kQ]     + bias[256 + rr];
                    float gv = av[4 * tq + 2] + pf[gb + 2 * kQ] + bias[512 + rr];
                    float ov = av[4 * tq + 3] + pf[gb + 3 * kQ] + bias[768 + rr];
                    float cc = sigm(fv) * c0p[((size_t)n * 256 + rr) * kQ + pxe]
                             + sigm(iv) * tanh_f(gv);
                    float hh = sigm(ov) * tanh_f(cc);
                    h16o[((size_t)n * kQ + pxe) * 256 + rr] = (_Float16)hh;
                }
            }
        }
        return;
    }
    const int mb0 = mt * 256 + wv * 64;
    #pragma unroll
    for (int mi = 0; mi < 2; ++mi) {
        #pragma unroll
        for (int ci = 0; ci < 2; ++ci) {
            const floatx16& av = mi ? (ci ? acc11 : acc10) : (ci ? acc01 : acc00);
            const int pxe = nt * 64 + ci * 32 + l31;
            #pragma unroll
            for (int r = 0; r < 16; ++r) {
                int rowi = (r & 3) + 8 * (r >> 2) + 4 * hl;
                int m = mb0 + mi * 32 + rowi;
                float val = av[r];
                if (EMODE == 0) {
                    if (m < 256) {
                        q16[((size_t)n * 256 + m) * kQ + pxe] = (_Float16)val;
                    } else if (m < 768) {
                        int ch = m & 255;
                        int yy = pxe / kHW, xx = pxe - yy * kHW;
                        if (yy >= 1 && yy <= 22 && xx >= 1 && xx <= 22) {
                            int d = (yy - 1) * 22 + (xx - 1);
                            int head = n * 8 + (ch >> 5);
                            if (m < 512)
                                k16[((size_t)head * kDP + d) * 32 + (ch & 31)] = (_Float16)val;
                            else
                                v16[((size_t)head * 32 + (ch & 31)) * kDP + d] = (_Float16)(val + bias[ch]);
                        }
                    } else {
                        pf[((size_t)n * 1024 + (m - 768)) * kQ + pxe] = val;
                    }
                } else {
                    pf[((size_t)n * 256 + m) * kQ + pxe] = val + bias[m];
                }
            }
        }
    }
}

// ---------------- MFMA flash attention ----------------
__global__ __launch_bounds__(128)
void attn_kernel(const _Float16* __restrict__ q16c, const _Float16* __restrict__ kT16,
                 const _Float16* __restrict__ vC16, _Float16* __restrict__ a16) {
    const int lane = threadIdx.x & 63;
    const int wv   = threadIdx.x >> 6;
    const int l31 = lane & 31, hl = lane >> 5;
    // XCD-chunked swizzle (1152 blocks, 144/XCD): same-head blocks stay on one XCD
    const int lid = blockIdx.x + 9 * blockIdx.y;
    const int swz = (lid & 7) * 144 + (lid >> 3);
    const int bx = swz % 9, head = swz / 9;     // head = n*8 + hd
    const int n = head >> 3, hd = head & 7;
    const int qt = bx * 2 + wv;                 // 0..17
    const int q0 = qt * 32;

    half8 qf0, qf1;
    {
        const _Float16* qb = q16c + ((size_t)n * 256 + hd * 32 + hl * 8) * kQ + q0 + l31;
        #pragma unroll
        for (int j = 0; j < 8; ++j) {
            qf0[j] = qb[(size_t)j * kQ];
            qf1[j] = qb[(size_t)(16 + j) * kQ];
        }
    }

    const _Float16* kbase0 = kT16 + ((size_t)head * kDP + l31) * 32 + hl * 8;
    const _Float16* vbase0 = vC16 + ((size_t)head * 32 + l31) * kDP + hl * 8;

    floatx16 acc = {};
    float m_run = -1e30f, l_run = 0.f;

    half8 kf0 = LD8(kbase0);
    half8 kf1 = LD8(kbase0 + 16);

    for (int dt = 0; dt < 16; ++dt) {
        const int d0 = dt * 32;
        floatx16 S = {};
        S = __builtin_amdgcn_mfma_f32_32x32x16_f16(kf0, qf0, S, 0, 0, 0);
        S = __builtin_amdgcn_mfma_f32_32x32x16_f16(kf1, qf1, S, 0, 0, 0);

        half8 vf0 = LD8(vbase0 + d0);
        half8 vf1 = LD8(vbase0 + d0 + 16);
        if (dt < 15) {
            kf0 = LD8(kbase0 + (size_t)(d0 + 32) * 32);
            kf1 = LD8(kbase0 + (size_t)(d0 + 32) * 32 + 16);
        }

        if (dt == 15) {
            #pragma unroll
            for (int r = 0; r < 16; ++r)
                if (!(hl == 0 && r < 4)) S[r] = -1e30f;
        }

        float tmax = S[0];
        #pragma unroll
        for (int r = 1; r < 16; ++r) tmax = fmaxf(tmax, S[r]);
        tmax = fmaxf(tmax, __shfl_xor(tmax, 32));
        float mnew = fmaxf(m_run, tmax);
        float f = __expf(m_run - mnew);
        float p[16], psum = 0.f;
        #pragma unroll
        for (int r = 0; r < 16; ++r) { p[r] = __expf(S[r] - mnew); psum += p[r]; }
        psum += __shfl_xor(psum, 32);
        l_run = f * l_run + psum;
        #pragma unroll
        for (int r = 0; r < 16; ++r) acc[r] *= f;
        m_run = mnew;

        float other[16];
        #pragma unroll
        for (int r = 0; r < 16; ++r) other[r] = __shfl_xor(p[r], 32);
        half8 pf0, pf1;
        #pragma unroll
        for (int t = 0; t < 4; ++t) {
            pf0[t]     = (_Float16)(hl ? other[4 + t]  : p[t]);
            pf0[4 + t] = (_Float16)(hl ? p[4 + t]      : other[t]);
            pf1[t]     = (_Float16)(hl ? other[12 + t] : p[8 + t]);
            pf1[4 + t] = (_Float16)(hl ? p[12 + t]     : other[8 + t]);
        }

        acc = __builtin_amdgcn_mfma_f32_32x32x16_f16(vf0, pf0, acc, 0, 0, 0);
        acc = __builtin_amdgcn_mfma_f32_32x32x16_f16(vf1, pf1, acc, 0, 0, 0);
    }

    float inv = 1.f / l_run;
    _Float16* ap = a16 + ((size_t)n * kQ + q0 + l31) * 256 + hd * 32;
    #pragma unroll
    for (int r = 0; r < 16; ++r) {
        int c = (r & 3) + 8 * (r >> 2) + 4 * hl;
        ap[c] = (_Float16)(acc[r] * inv);
    }
}

extern "C" void kernel_launch(void* const* d_in, const int* in_sizes, int n_in,
                              void* d_out, int out_size, void* d_ws, size_t ws_size,
                              hipStream_t stream) {
    (void)in_sizes; (void)n_in; (void)out_size; (void)ws_size;
    const float* x     = (const float*)d_in[0];
    const float* h0    = (const float*)d_in[1];
    const float* c0    = (const float*)d_in[2];
    const float* w_in  = (const float*)d_in[3];
    const float* b_in  = (const float*)d_in[4];
    const float* wq_x  = (const float*)d_in[5];
    const float* wq_h  = (const float*)d_in[6];
    const float* wk_x  = (const float*)d_in[7];
    const float* wk_h  = (const float*)d_in[8];
    const float* wv_x  = (const float*)d_in[9];
    const float* wv_h  = (const float*)d_in[10];
    const float* bv    = (const float*)d_in[11];
    const float* wg_a  = (const float*)d_in[12];
    const float* bg    = (const float*)d_in[13];
    const float* wg_x  = (const float*)d_in[14];
    const float* wg_h  = (const float*)d_in[15];
    const float* w_out = (const float*)d_in[16];
    const float* b_out = (const float*)d_in[17];

    _Float16* wh = (_Float16*)d_ws;
    _Float16* xpad16  = wh + H_XPAD;
    _Float16* hpad16  = wh + H_HPAD;
    _Float16* apack1  = wh + H_APACK1;
    _Float16* apack2  = wh + H_APACK2;
    _Float16* apack3  = wh + H_APACK3;
    _Float16* a16     = wh + H_A16;
    _Float16* h16     = wh + H_H16;
    _Float16* q16c    = wh + H_Q16C;
    _Float16* kT16    = wh + H_KT16;
    _Float16* vC16    = wh + H_VC16;
    float* gbuf = (float*)((char*)d_ws + HALF_BYTES) + F_G;

    // zero NHWC image borders (ws re-poisoned each launch)
    hipMemsetAsync(wh, 0, 11075584, stream);

    // weight packing (fragment-order, 256-row tiles; gate rows interleaved)
    pack1_kernel<<<4032, 256, 0, stream>>>(wq_x, wq_h, wk_x, wk_h, wv_x, wv_h, wg_x, wg_h, apack1);
    pack_flat_kernel<1><<<128, 256, 0, stream>>>(wg_a, apack2, 256, kKT2);
    pack_flat_kernel<0><<<32, 256, 0, stream>>>(w_out, apack3, 256, kKT3);

    // input staging (NHWC fp16)
    pad_nhwc_kernel<<<dim3(9, 8, kN), 256, 0, stream>>>(h0, hpad16);
    conv1x1_pad_kernel<<<dim3(9, 16, kN), dim3(64, 4), 0, stream>>>(x, w_in, b_in, xpad16);

    // fused q/k/v/gates3x3 GEMM: M=1792, K=4608, N=576 x 16 batches
    // natural grid order (x=nt fast) — blocks stay kt-synchronized for L1/L2 A-sharing
    gemm_kernel<0, 0><<<dim3(9, kN, 7), 256, 0, stream>>>(
        apack1, xpad16, hpad16, q16c, kT16, vC16, gbuf, bv, nullptr, nullptr, kKT1, 0);

    // MFMA flash attention -> a16 [n][px][256]
    attn_kernel<<<dim3(9, 128), 128, 0, stream>>>(q16c, kT16, vC16, a16);

    // gates = wg_a . a + bg + gbuf, fused LSTM -> h16 [n][px][256]
    gemm_kernel<1, 3><<<dim3(9, kN, 4), 256, 0, stream>>>(
        apack2, a16, nullptr, nullptr, nullptr, nullptr, gbuf, bg, c0, h16, kKT2, 256);

    // out = w_out . h + b_out : M=256 -> 1 m-tile
    gemm_kernel<1, 2><<<dim3(9, kN, 1), 256, 0, stream>>>(
        apack3, h16, nullptr, nullptr, nullptr, nullptr, (float*)d_out, b_out, nullptr, nullptr, kKT3, 256);
}

// Round 5
// 404.828 us; speedup vs baseline: 1.4139x; 1.0368x over previous
//
#include <hip/hip_runtime.h>
#include <cstddef>

// ---- problem constants ----
constexpr int kN  = 16;
constexpr int kI  = 128;
constexpr int kHW = 24;
constexpr int kQ  = 576;    // 24*24
constexpr int kD  = 484;    // 22*22
constexpr int kDP = 512;    // padded d
constexpr int kPP = 676;    // 26*26 padded

// GEMM K-tiling (BK=64)
constexpr int kKT1 = 72;    // K1 = 4608 / 64
constexpr int kKT2 = 4;     // K2 = 256 / 64
constexpr int kKT3 = 4;     // K3 = 256 / 64

// ---- workspace layout ----
// half region (element offsets into _Float16*)
constexpr size_t H_XPAD   = 0;                          // [16][26][26][256] NHWC
constexpr size_t H_HPAD   = 2768896;                    // [16][26][26][256] NHWC
constexpr size_t H_APACK1 = 5537792;                    // 1792*4608 frag-tiled (256-row, BK64)
constexpr size_t H_APACK2 = 13795328;                   // 1024*256 frag-tiled
constexpr size_t H_APACK3 = 14057472;                   // 256*256 frag-tiled
constexpr size_t H_A16    = 14123008;                   // [16][576][256]
constexpr size_t H_H16    = 16482304;                   // [16][576][256]
constexpr size_t H_Q16C   = 18841600;                   // [16][256][576]  (c-major)
constexpr size_t H_KT16   = 21200896;                   // [128 head][512 d][32 c]
constexpr size_t H_VC16   = 23298048;                   // [128 head][32 c][512 d]
constexpr size_t HALF_ELEMS = 25395200;
constexpr size_t HALF_BYTES = HALF_ELEMS * 2;           // 50,790,400
// float region at d_ws + HALF_BYTES
constexpr size_t F_G = 0;                               // [16][1024][576]

constexpr size_t kXHGap = H_HPAD - H_XPAD;              // hpad - xpad element gap

using half8    = __attribute__((ext_vector_type(8))) _Float16;
using floatx16 = __attribute__((ext_vector_type(16))) float;

__device__ __forceinline__ float sigm(float x) { return 1.0f / (1.0f + __expf(-x)); }
__device__ __forceinline__ float tanh_f(float x) {
    float e = __expf(2.0f * fabsf(x));
    float r = 1.0f - 2.0f / (e + 1.0f);
    return copysignf(r, x);
}

// 16B-aligned vector load/store (emits b128 ops)
__device__ __forceinline__ half8 LD8(const _Float16* p) { return *(const half8*)p; }
__device__ __forceinline__ void ST8(_Float16* p, half8 v) { *(half8*)p = v; }

// ---------------- weight packing ----------------
// Apack layout (BK=64): [mt][kt][kk(4)][hl(2)][row(256)][j(8)] — exact A-fragment
// order, 256-row M-tiles. One half8 per thread.
// K-order for gemm1: k = src*2304 + tap*256 + ic
// Gate rows (m>=768) PERMUTED: dst row m' = 4*r + gate for the fused LSTM epilogue.
__global__ void pack1_kernel(const float* __restrict__ wq_x, const float* __restrict__ wq_h,
                             const float* __restrict__ wk_x, const float* __restrict__ wk_h,
                             const float* __restrict__ wv_x, const float* __restrict__ wv_h,
                             const float* __restrict__ wg_x, const float* __restrict__ wg_h,
                             _Float16* __restrict__ dst) {
    int p8 = blockIdx.x * 256 + threadIdx.x;           // one half8 per thread
    int row = p8 & 255, hl = (p8 >> 8) & 1, kk = (p8 >> 9) & 3;
    int tile = p8 >> 11;
    int mt = tile / kKT1, kt = tile - mt * kKT1;
    int m = mt * 256 + row;
    int k0 = kt * 64 + kk * 16 + hl * 8;               // j=0..7 contiguous in k
    int srcs = (k0 >= 2304) ? 1 : 0;
    int r = k0 - srcs * 2304;
    int tap = r >> 8, ic0 = r & 255;                   // 8-aligned: tap/srcs j-invariant
    const float *s1, *s2; int mm;
    if (m < 256)      { s1 = wq_x; s2 = wq_h; mm = m; }
    else if (m < 512) { s1 = wk_x; s2 = wk_h; mm = m - 256; }
    else if (m < 768) { s1 = wv_x; s2 = wv_h; mm = m - 512; }
    else              { s1 = wg_x; s2 = wg_h; int mp = m - 768; mm = (mp & 3) * 256 + (mp >> 2); }
    const float* sp = (srcs ? s2 : s1) + (size_t)mm * 2304 + ic0 * 9 + tap;
    half8 v;
    #pragma unroll
    for (int j = 0; j < 8; ++j) v[j] = (_Float16)sp[j * 9];
    ST8(dst + (size_t)p8 * 8, v);
}

// PERM=1: dst row m <- src row (m&3)*256 + (m>>2)  (gate interleave for wg_a)
template<int PERM>
__global__ void pack_flat_kernel(const float* __restrict__ src, _Float16* __restrict__ dst,
                                 int Ktot, int Ktiles) {
    int p8 = blockIdx.x * 256 + threadIdx.x;           // one half8 per thread
    int row = p8 & 255, hl = (p8 >> 8) & 1, kk = (p8 >> 9) & 3;
    int tile = p8 >> 11;
    int mt = tile / Ktiles, kt = tile - mt * Ktiles;
    int m = mt * 256 + row;
    int k0 = kt * 64 + kk * 16 + hl * 8;
    int mm = PERM ? ((m & 3) * 256 + (m >> 2)) : m;
    const float* sp = src + (size_t)mm * Ktot + k0;
    half8 v;
    #pragma unroll
    for (int j = 0; j < 8; ++j) v[j] = (_Float16)sp[j];
    ST8(dst + (size_t)p8 * 8, v);
}

// ---------------- input staging ----------------
// h0 [n][256][576] fp32 -> NHWC fp16 padded [n][26][26][256] (borders pre-zeroed)
__global__ void pad_nhwc_kernel(const float* __restrict__ src, _Float16* __restrict__ dst) {
    __shared__ float tile[32][65];
    int pxt = blockIdx.x, ict = blockIdx.y, n = blockIdx.z;
    int tid = threadIdx.x;
    {
        int icl = tid >> 6, pxl = tid & 63;
        #pragma unroll
        for (int rep = 0; rep < 8; ++rep) {
            int ic = ict * 32 + rep * 4 + icl;
            tile[rep * 4 + icl][pxl] = src[((size_t)n * 256 + ic) * kQ + pxt * 64 + pxl];
        }
    }
    __syncthreads();
    {
        int icl = tid & 31, pxl0 = tid >> 5;
        #pragma unroll
        for (int rep = 0; rep < 8; ++rep) {
            int pxl = rep * 8 + pxl0;
            int px = pxt * 64 + pxl;
            int y = px / kHW, x = px - y * kHW;
            dst[((size_t)n * kPP + (size_t)(y + 1) * 26 + (x + 1)) * 256 + ict * 32 + icl] =
                (_Float16)tile[icl][pxl];
        }
    }
}

// xin = 1x1 conv(x, w_in)+b_in -> NHWC fp16 padded
__global__ void conv1x1_pad_kernel(const float* __restrict__ x, const float* __restrict__ w,
                                   const float* __restrict__ b, _Float16* __restrict__ out) {
    int px = blockIdx.x * 64 + threadIdx.x;
    int n = blockIdx.z;
    int oc0 = __builtin_amdgcn_readfirstlane(blockIdx.y * 16 + threadIdx.y * 4);
    const float* ip = x + (size_t)n * kI * kQ + px;
    float acc[4] = {0.f, 0.f, 0.f, 0.f};
    #pragma unroll 4
    for (int ic = 0; ic < kI; ++ic) {
        float xv = ip[(size_t)ic * kQ];
        #pragma unroll
        for (int j = 0; j < 4; ++j) acc[j] = fmaf(xv, w[(size_t)(oc0 + j) * kI + ic], acc[j]);
    }
    int y = px / kHW, xc = px - y * kHW;
    _Float16* op = out + ((size_t)n * kPP + (size_t)(y + 1) * 26 + (xc + 1)) * 256 + oc0;
    #pragma unroll
    for (int j = 0; j < 4; ++j) op[j] = (_Float16)(acc[j] + b[oc0 + j]);
}

// ---------------- fused MFMA GEMM (BK=64) ----------------
// BM=256, BN=64, BK=64; 256 threads = 4 waves; wave wv owns rows wv*64..+63
// (2 m-frags x 2 n-frags = 4 accs/wave). 16 MFMA per wave per K-step — 2x the
// MFMA work per barrier vs BK=32 (R4's counted-vmcnt barriers kept).
// A: rolling register prefetch: kkc01 frags cross-step; kkc23 loaded at step
//    start (consumed after 8 MFMAs); next-step kkc01 issued mid-MFMA-cluster.
// B: 2 half8/thread -> swizzled LDS [px64][chunk8 ^ (px&7)][8] (128B rows),
//    double-buffered (2x8KB), 2-tile-deep register staging.
// Swizzle is bank-balanced: every b128 op lands exactly 8 lanes per 16B slot.
// BMODE 0: B = on-the-fly im2col from two NHWC fp16 images, K=(src,tap,ic)
// BMODE 1: B = direct [n][576][Ktot] fp16 (channel-last)
// EMODE 0: m<256 -> q16c; 256..511 -> kT16; 512..767 -> vC16(+bias); 768.. -> gbuf
// EMODE 2: out = acc + bias[m] -> pf
// EMODE 3: fused gate+LSTM epilogue (gate rows interleaved m'=4r+g)
template<int BMODE, int EMODE>
__global__ __launch_bounds__(256, 3)
void gemm_kernel(const _Float16* __restrict__ Apack,
                 const _Float16* __restrict__ B1, const _Float16* __restrict__ B2,
                 _Float16* __restrict__ q16, _Float16* __restrict__ k16,
                 _Float16* __restrict__ v16, float* __restrict__ pf,
                 const float* __restrict__ bias, const float* __restrict__ c0p,
                 _Float16* __restrict__ h16o, int Ktiles, int Ktot) {
    __shared__ _Float16 Bs[2][4096];
    const int tid = threadIdx.x;
    const int wv = tid >> 6, lane = tid & 63, l31 = lane & 31, hl = lane >> 5;
    const int nt = blockIdx.x, n = blockIdx.y, mt = blockIdx.z;

    floatx16 acc00 = {}, acc01 = {}, acc10 = {}, acc11 = {};

    // A packed [mt][kt][kk4][hl2][row256][j8]; per-kt tile = 16384 elems
    const _Float16* abase = Apack + (size_t)mt * Ktiles * 16384;
    const int aoff = hl * 2048 + (wv * 64 + l31) * 8;      // + mi*256 + kk*4096

    // B staging: thread (px_l, bc) loads k-local [bc*16, +16) of row px_l
    const int px_l = tid >> 2, bc = tid & 3;
    const int px = nt * 64 + px_l;
    const int by = px / kHW, bx = px - by * kHW;

    // LDS swizzle: chunk ^= row&7 (8 chunks of 16B per 128B row)
    const int sw = px_l & 7;
    const int wofs0 = px_l * 64 + (((2 * bc) ^ sw) << 3);
    const int wofs1 = px_l * 64 + (((2 * bc + 1) ^ sw) << 3);
    const int rsw = l31 & 7;
    const int ro0 = l31 * 64 + (((0 + hl) ^ rsw) << 3);    // kkc0; +2048 for ci=1
    const int ro1 = l31 * 64 + (((2 + hl) ^ rsw) << 3);
    const int ro2 = l31 * 64 + (((4 + hl) ^ rsw) << 3);
    const int ro3 = l31 * 64 + (((6 + hl) ^ rsw) << 3);

    const _Float16* bsx;
    if (BMODE == 0) {
        bsx = B1 + ((size_t)n * kPP + (size_t)by * 26 + bx) * 256 + (size_t)bc * 16;
    } else {
        bsx = B1 + ((size_t)n * kQ + px) * Ktot + bc * 16;
    }

    auto loadB = [&](int kt, half8& lo, half8& hi) {
        if (BMODE == 0) {
            int srcs = (kt >= 36) ? 1 : 0;
            int ktl = kt - srcs * 36;
            int tap = ktl >> 2, icb = (ktl & 3) << 6;
            int ty = (tap * 11) >> 5;          // tap/3 for 0..9
            int tx = tap - ty * 3;
            const _Float16* p = bsx + (size_t)srcs * kXHGap
                              + ((size_t)(ty * 26 + tx)) * 256 + icb;
            lo = LD8(p); hi = LD8(p + 8);
        } else {
            const _Float16* p = bsx + kt * 64;
            lo = LD8(p); hi = LD8(p + 8);
        }
    };

    // prologue: B two tiles deep; A kkc01 of step 0
    half8 s0lo, s0hi, s1lo, s1hi;
    loadB(0, s0lo, s0hi);
    loadB(1, s1lo, s1hi);
    half8 eA = LD8(abase + aoff),        eB = LD8(abase + aoff + 256);
    half8 eC = LD8(abase + 4096 + aoff), eD = LD8(abase + 4096 + aoff + 256);
    half8 oA, oB, oC, oD;

    for (int kt = 0; kt < Ktiles; kt += 2) {
        const _Float16* ab = abase + (size_t)kt * 16384;
        // ---- even step: buffer 0 holds tile kt ----
        ST8(&Bs[0][wofs0], s0lo); ST8(&Bs[0][wofs1], s0hi);
        loadB(kt + 2, s0lo, s0hi);                          // 2-deep B prefetch
        asm volatile("s_waitcnt lgkmcnt(0)" ::: "memory");
        __builtin_amdgcn_s_barrier();                       // raw: no vmcnt drain
        {
            const _Float16* bb = Bs[0];
            half8 f0 = LD8(ab + 8192 + aoff),  f1 = LD8(ab + 8192 + aoff + 256);   // kkc2
            half8 f2 = LD8(ab + 12288 + aoff), f3 = LD8(ab + 12288 + aoff + 256);  // kkc3
            half8 b00 = LD8(bb + ro0), b01 = LD8(bb + ro0 + 2048);
            half8 b10 = LD8(bb + ro1), b11 = LD8(bb + ro1 + 2048);
            half8 b20 = LD8(bb + ro2), b21 = LD8(bb + ro2 + 2048);
            half8 b30 = LD8(bb + ro3), b31 = LD8(bb + ro3 + 2048);
            __builtin_amdgcn_s_setprio(1);
            acc00 = __builtin_amdgcn_mfma_f32_32x32x16_f16(eA, b00, acc00, 0, 0, 0);
            acc01 = __builtin_amdgcn_mfma_f32_32x32x16_f16(eA, b01, acc01, 0, 0, 0);
            acc10 = __builtin_amdgcn_mfma_f32_32x32x16_f16(eB, b00, acc10, 0, 0, 0);
            acc11 = __builtin_amdgcn_mfma_f32_32x32x16_f16(eB, b01, acc11, 0, 0, 0);
            acc00 = __builtin_amdgcn_mfma_f32_32x32x16_f16(eC, b10, acc00, 0, 0, 0);
            acc01 = __builtin_amdgcn_mfma_f32_32x32x16_f16(eC, b11, acc01, 0, 0, 0);
            acc10 = __builtin_amdgcn_mfma_f32_32x32x16_f16(eD, b10, acc10, 0, 0, 0);
            acc11 = __builtin_amdgcn_mfma_f32_32x32x16_f16(eD, b11, acc11, 0, 0, 0);
            __builtin_amdgcn_s_setprio(0);
            oA = LD8(ab + 16384 + aoff);        oB = LD8(ab + 16384 + aoff + 256); // next kkc01
            oC = LD8(ab + 16384 + 4096 + aoff); oD = LD8(ab + 16384 + 4096 + aoff + 256);
            __builtin_amdgcn_s_setprio(1);
            acc00 = __builtin_amdgcn_mfma_f32_32x32x16_f16(f0, b20, acc00, 0, 0, 0);
            acc01 = __builtin_amdgcn_mfma_f32_32x32x16_f16(f0, b21, acc01, 0, 0, 0);
            acc10 = __builtin_amdgcn_mfma_f32_32x32x16_f16(f1, b20, acc10, 0, 0, 0);
            acc11 = __builtin_amdgcn_mfma_f32_32x32x16_f16(f1, b21, acc11, 0, 0, 0);
            acc00 = __builtin_amdgcn_mfma_f32_32x32x16_f16(f2, b30, acc00, 0, 0, 0);
            acc01 = __builtin_amdgcn_mfma_f32_32x32x16_f16(f2, b31, acc01, 0, 0, 0);
            acc10 = __builtin_amdgcn_mfma_f32_32x32x16_f16(f3, b30, acc10, 0, 0, 0);
            acc11 = __builtin_amdgcn_mfma_f32_32x32x16_f16(f3, b31, acc11, 0, 0, 0);
            __builtin_amdgcn_s_setprio(0);
        }
        // ---- odd step: buffer 1 holds tile kt+1 ----
        const _Float16* ab2 = ab + 16384;
        ST8(&Bs[1][wofs0], s1lo); ST8(&Bs[1][wofs1], s1hi);
        loadB(kt + 3, s1lo, s1hi);
        asm volatile("s_waitcnt lgkmcnt(0)" ::: "memory");
        __builtin_amdgcn_s_barrier();
        {
            const _Float16* bb = Bs[1];
            half8 g0 = LD8(ab2 + 8192 + aoff),  g1 = LD8(ab2 + 8192 + aoff + 256);
            half8 g2 = LD8(ab2 + 12288 + aoff), g3 = LD8(ab2 + 12288 + aoff + 256);
            half8 b00 = LD8(bb + ro0), b01 = LD8(bb + ro0 + 2048);
            half8 b10 = LD8(bb + ro1), b11 = LD8(bb + ro1 + 2048);
            half8 b20 = LD8(bb + ro2), b21 = LD8(bb + ro2 + 2048);
            half8 b30 = LD8(bb + ro3), b31 = LD8(bb + ro3 + 2048);
            __builtin_amdgcn_s_setprio(1);
            acc00 = __builtin_amdgcn_mfma_f32_32x32x16_f16(oA, b00, acc00, 0, 0, 0);
            acc01 = __builtin_amdgcn_mfma_f32_32x32x16_f16(oA, b01, acc01, 0, 0, 0);
            acc10 = __builtin_amdgcn_mfma_f32_32x32x16_f16(oB, b00, acc10, 0, 0, 0);
            acc11 = __builtin_amdgcn_mfma_f32_32x32x16_f16(oB, b01, acc11, 0, 0, 0);
            acc00 = __builtin_amdgcn_mfma_f32_32x32x16_f16(oC, b10, acc00, 0, 0, 0);
            acc01 = __builtin_amdgcn_mfma_f32_32x32x16_f16(oC, b11, acc01, 0, 0, 0);
            acc10 = __builtin_amdgcn_mfma_f32_32x32x16_f16(oD, b10, acc10, 0, 0, 0);
            acc11 = __builtin_amdgcn_mfma_f32_32x32x16_f16(oD, b11, acc11, 0, 0, 0);
            __builtin_amdgcn_s_setprio(0);
            eA = LD8(ab2 + 16384 + aoff);        eB = LD8(ab2 + 16384 + aoff + 256);
            eC = LD8(ab2 + 16384 + 4096 + aoff); eD = LD8(ab2 + 16384 + 4096 + aoff + 256);
            __builtin_amdgcn_s_setprio(1);
            acc00 = __builtin_amdgcn_mfma_f32_32x32x16_f16(g0, b20, acc00, 0, 0, 0);
            acc01 = __builtin_amdgcn_mfma_f32_32x32x16_f16(g0, b21, acc01, 0, 0, 0);
            acc10 = __builtin_amdgcn_mfma_f32_32x32x16_f16(g1, b20, acc10, 0, 0, 0);
            acc11 = __builtin_amdgcn_mfma_f32_32x32x16_f16(g1, b21, acc11, 0, 0, 0);
            acc00 = __builtin_amdgcn_mfma_f32_32x32x16_f16(g2, b30, acc00, 0, 0, 0);
            acc01 = __builtin_amdgcn_mfma_f32_32x32x16_f16(g2, b31, acc01, 0, 0, 0);
            acc10 = __builtin_amdgcn_mfma_f32_32x32x16_f16(g3, b30, acc10, 0, 0, 0);
            acc11 = __builtin_amdgcn_mfma_f32_32x32x16_f16(g3, b31, acc11, 0, 0, 0);
            __builtin_amdgcn_s_setprio(0);
        }
    }

    // epilogue: C/D layout col=lane&31, row=(reg&3)+8*(reg>>2)+4*(lane>>5)
    if (EMODE == 3) {
        // fused gates+LSTM: reg q holds gate g=q&3 of channel rr (4 gates per reg-quad)
        const int rrb = mt * 64 + wv * 16;
        #pragma unroll
        for (int mi = 0; mi < 2; ++mi) {
            #pragma unroll
            for (int ci = 0; ci < 2; ++ci) {
                const floatx16& av = mi ? (ci ? acc11 : acc10) : (ci ? acc01 : acc00);
                const int pxe = nt * 64 + ci * 32 + l31;
                #pragma unroll
                for (int tq = 0; tq < 4; ++tq) {
                    int rr = rrb + mi * 8 + 2 * tq + hl;
                    size_t gb = ((size_t)n * 1024 + 4 * rr) * kQ + pxe;
                    float iv = av[4 * tq + 0] + pf[gb]          + bias[rr];
                    float fv = av[4 * tq + 1] + pf[gb + kQ]     + bias[256 + rr];
                    float gv = av[4 * tq + 2] + pf[gb + 2 * kQ] + bias[512 + rr];
                    float ov = av[4 * tq + 3] + pf[gb + 3 * kQ] + bias[768 + rr];
                    float cc = sigm(fv) * c0p[((size_t)n * 256 + rr) * kQ + pxe]
                             + sigm(iv) * tanh_f(gv);
                    float hh = sigm(ov) * tanh_f(cc);
                    h16o[((size_t)n * kQ + pxe) * 256 + rr] = (_Float16)hh;
                }
            }
        }
        return;
    }
    const int mb0 = mt * 256 + wv * 64;
    #pragma unroll
    for (int mi = 0; mi < 2; ++mi) {
        #pragma unroll
        for (int ci = 0; ci < 2; ++ci) {
            const floatx16& av = mi ? (ci ? acc11 : acc10) : (ci ? acc01 : acc00);
            const int pxe = nt * 64 + ci * 32 + l31;
            #pragma unroll
            for (int r = 0; r < 16; ++r) {
                int rowi = (r & 3) + 8 * (r >> 2) + 4 * hl;
                int m = mb0 + mi * 32 + rowi;
                float val = av[r];
                if (EMODE == 0) {
                    if (m < 256) {
                        q16[((size_t)n * 256 + m) * kQ + pxe] = (_Float16)val;
                    } else if (m < 768) {
                        int ch = m & 255;
                        int yy = pxe / kHW, xx = pxe - yy * kHW;
                        if (yy >= 1 && yy <= 22 && xx >= 1 && xx <= 22) {
                            int d = (yy - 1) * 22 + (xx - 1);
                            int head = n * 8 + (ch >> 5);
                            if (m < 512)
                                k16[((size_t)head * kDP + d) * 32 + (ch & 31)] = (_Float16)val;
                            else
                                v16[((size_t)head * 32 + (ch & 31)) * kDP + d] = (_Float16)(val + bias[ch]);
                        }
                    } else {
                        pf[((size_t)n * 1024 + (m - 768)) * kQ + pxe] = val;
                    }
                } else {
                    pf[((size_t)n * 256 + m) * kQ + pxe] = val + bias[m];
                }
            }
        }
    }
}

// ---------------- MFMA flash attention ----------------
__global__ __launch_bounds__(128)
void attn_kernel(const _Float16* __restrict__ q16c, const _Float16* __restrict__ kT16,
                 const _Float16* __restrict__ vC16, _Float16* __restrict__ a16) {
    const int lane = threadIdx.x & 63;
    const int wv   = threadIdx.x >> 6;
    const int l31 = lane & 31, hl = lane >> 5;
    // XCD-chunked swizzle (1152 blocks, 144/XCD): same-head blocks stay on one XCD
    const int lid = blockIdx.x + 9 * blockIdx.y;
    const int swz = (lid & 7) * 144 + (lid >> 3);
    const int bx = swz % 9, head = swz / 9;     // head = n*8 + hd
    const int n = head >> 3, hd = head & 7;
    const int qt = bx * 2 + wv;                 // 0..17
    const int q0 = qt * 32;

    half8 qf0, qf1;
    {
        const _Float16* qb = q16c + ((size_t)n * 256 + hd * 32 + hl * 8) * kQ + q0 + l31;
        #pragma unroll
        for (int j = 0; j < 8; ++j) {
            qf0[j] = qb[(size_t)j * kQ];
            qf1[j] = qb[(size_t)(16 + j) * kQ];
        }
    }

    const _Float16* kbase0 = kT16 + ((size_t)head * kDP + l31) * 32 + hl * 8;
    const _Float16* vbase0 = vC16 + ((size_t)head * 32 + l31) * kDP + hl * 8;

    floatx16 acc = {};
    float m_run = -1e30f, l_run = 0.f;

    half8 kf0 = LD8(kbase0);
    half8 kf1 = LD8(kbase0 + 16);

    for (int dt = 0; dt < 16; ++dt) {
        const int d0 = dt * 32;
        floatx16 S = {};
        S = __builtin_amdgcn_mfma_f32_32x32x16_f16(kf0, qf0, S, 0, 0, 0);
        S = __builtin_amdgcn_mfma_f32_32x32x16_f16(kf1, qf1, S, 0, 0, 0);

        half8 vf0 = LD8(vbase0 + d0);
        half8 vf1 = LD8(vbase0 + d0 + 16);
        if (dt < 15) {
            kf0 = LD8(kbase0 + (size_t)(d0 + 32) * 32);
            kf1 = LD8(kbase0 + (size_t)(d0 + 32) * 32 + 16);
        }

        if (dt == 15) {
            #pragma unroll
            for (int r = 0; r < 16; ++r)
                if (!(hl == 0 && r < 4)) S[r] = -1e30f;
        }

        float tmax = S[0];
        #pragma unroll
        for (int r = 1; r < 16; ++r) tmax = fmaxf(tmax, S[r]);
        tmax = fmaxf(tmax, __shfl_xor(tmax, 32));
        float mnew = fmaxf(m_run, tmax);
        float f = __expf(m_run - mnew);
        float p[16], psum = 0.f;
        #pragma unroll
        for (int r = 0; r < 16; ++r) { p[r] = __expf(S[r] - mnew); psum += p[r]; }
        psum += __shfl_xor(psum, 32);
        l_run = f * l_run + psum;
        #pragma unroll
        for (int r = 0; r < 16; ++r) acc[r] *= f;
        m_run = mnew;

        float other[16];
        #pragma unroll
        for (int r = 0; r < 16; ++r) other[r] = __shfl_xor(p[r], 32);
        half8 pf0, pf1;
        #pragma unroll
        for (int t = 0; t < 4; ++t) {
            pf0[t]     = (_Float16)(hl ? other[4 + t]  : p[t]);
            pf0[4 + t] = (_Float16)(hl ? p[4 + t]      : other[t]);
            pf1[t]     = (_Float16)(hl ? other[12 + t] : p[8 + t]);
            pf1[4 + t] = (_Float16)(hl ? p[12 + t]     : other[8 + t]);
        }

        acc = __builtin_amdgcn_mfma_f32_32x32x16_f16(vf0, pf0, acc, 0, 0, 0);
        acc = __builtin_amdgcn_mfma_f32_32x32x16_f16(vf1, pf1, acc, 0, 0, 0);
    }

    float inv = 1.f / l_run;
    _Float16* ap = a16 + ((size_t)n * kQ + q0 + l31) * 256 + hd * 32;
    #pragma unroll
    for (int r = 0; r < 16; ++r) {
        int c = (r & 3) + 8 * (r >> 2) + 4 * hl;
        ap[c] = (_Float16)(acc[r] * inv);
    }
}

extern "C" void kernel_launch(void* const* d_in, const int* in_sizes, int n_in,
                              void* d_out, int out_size, void* d_ws, size_t ws_size,
                              hipStream_t stream) {
    (void)in_sizes; (void)n_in; (void)out_size; (void)ws_size;
    const float* x     = (const float*)d_in[0];
    const float* h0    = (const float*)d_in[1];
    const float* c0    = (const float*)d_in[2];
    const float* w_in  = (const float*)d_in[3];
    const float* b_in  = (const float*)d_in[4];
    const float* wq_x  = (const float*)d_in[5];
    const float* wq_h  = (const float*)d_in[6];
    const float* wk_x  = (const float*)d_in[7];
    const float* wk_h  = (const float*)d_in[8];
    const float* wv_x  = (const float*)d_in[9];
    const float* wv_h  = (const float*)d_in[10];
    const float* bv    = (const float*)d_in[11];
    const float* wg_a  = (const float*)d_in[12];
    const float* bg    = (const float*)d_in[13];
    const float* wg_x  = (const float*)d_in[14];
    const float* wg_h  = (const float*)d_in[15];
    const float* w_out = (const float*)d_in[16];
    const float* b_out = (const float*)d_in[17];

    _Float16* wh = (_Float16*)d_ws;
    _Float16* xpad16  = wh + H_XPAD;
    _Float16* hpad16  = wh + H_HPAD;
    _Float16* apack1  = wh + H_APACK1;
    _Float16* apack2  = wh + H_APACK2;
    _Float16* apack3  = wh + H_APACK3;
    _Float16* a16     = wh + H_A16;
    _Float16* h16     = wh + H_H16;
    _Float16* q16c    = wh + H_Q16C;
    _Float16* kT16    = wh + H_KT16;
    _Float16* vC16    = wh + H_VC16;
    float* gbuf = (float*)((char*)d_ws + HALF_BYTES) + F_G;

    // zero NHWC image borders (ws re-poisoned each launch)
    hipMemsetAsync(wh, 0, 11075584, stream);

    // weight packing (fragment-order BK=64 tiles; gate rows interleaved)
    pack1_kernel<<<4032, 256, 0, stream>>>(wq_x, wq_h, wk_x, wk_h, wv_x, wv_h, wg_x, wg_h, apack1);
    pack_flat_kernel<1><<<128, 256, 0, stream>>>(wg_a, apack2, 256, kKT2);
    pack_flat_kernel<0><<<32, 256, 0, stream>>>(w_out, apack3, 256, kKT3);

    // input staging (NHWC fp16)
    pad_nhwc_kernel<<<dim3(9, 8, kN), 256, 0, stream>>>(h0, hpad16);
    conv1x1_pad_kernel<<<dim3(9, 16, kN), dim3(64, 4), 0, stream>>>(x, w_in, b_in, xpad16);

    // fused q/k/v/gates3x3 GEMM: M=1792, K=4608, N=576 x 16 batches
    gemm_kernel<0, 0><<<dim3(9, kN, 7), 256, 0, stream>>>(
        apack1, xpad16, hpad16, q16c, kT16, vC16, gbuf, bv, nullptr, nullptr, kKT1, 0);

    // MFMA flash attention -> a16 [n][px][256]
    attn_kernel<<<dim3(9, 128), 128, 0, stream>>>(q16c, kT16, vC16, a16);

    // gates = wg_a . a + bg + gbuf, fused LSTM -> h16 [n][px][256]
    gemm_kernel<1, 3><<<dim3(9, kN, 4), 256, 0, stream>>>(
        apack2, a16, nullptr, nullptr, nullptr, nullptr, gbuf, bg, c0, h16, kKT2, 256);

    // out = w_out . h + b_out : M=256 -> 1 m-tile
    gemm_kernel<1, 2><<<dim3(9, kN, 1), 256, 0, stream>>>(
        apack3, h16, nullptr, nullptr, nullptr, nullptr, (float*)d_out, b_out, nullptr, nullptr, kKT3, 256);
}